// Round 1
// baseline (587.962 us; speedup 1.0000x reference)
//
#include <hip/hip_runtime.h>
#include <stdint.h>
#include <stddef.h>

// Problem constants
#define BROWS 8192
#define FEATK 7680
#define HIDN  512

typedef __attribute__((ext_vector_type(8))) __bf16 bf16x8;
typedef __attribute__((ext_vector_type(4))) float f32x4;

// fp32 -> bf16 round-to-nearest-even (bit manip; inputs finite)
__device__ __forceinline__ unsigned short f2b(float f) {
  unsigned int u = __float_as_uint(f);
  unsigned int r = (u + 0x7FFFu + ((u >> 16) & 1u)) >> 16;
  return (unsigned short)r;
}
__device__ __forceinline__ float b2f(unsigned short s) {
  return __uint_as_float(((unsigned int)s) << 16);
}

// ---------------- K0: fp32 -> bf16 conversion (vectorized, grid-stride) ----------------
__global__ void cvt_kernel(const float* __restrict__ src, unsigned short* __restrict__ dst, int n4) {
  int i = blockIdx.x * blockDim.x + threadIdx.x;
  int stride = gridDim.x * blockDim.x;
  for (; i < n4; i += stride) {
    float4 v = ((const float4*)src)[i];
    ushort4 o;
    o.x = f2b(v.x); o.y = f2b(v.y); o.z = f2b(v.z); o.w = f2b(v.w);
    ((ushort4*)dst)[i] = o;
  }
}

// ---------------- K1/K2: bf16 GEMM  C = relu(A @ B^T + bias) ----------------
// A: [M,K] bf16 row-major; Bm: [N,K] bf16 row-major (torch Linear weight layout);
// C: [M,N] bf16. 128x128 block tile, BK=64, 256 threads (2x2 waves of 64x64),
// 16x16x32 bf16 MFMA, global_load_lds width=16 staging (m97 structure).
#define BM 128
#define BN 128
#define BK 64

__global__ __launch_bounds__(256, 2) void gemm_bt_bias_relu(
    const unsigned short* __restrict__ A,
    const unsigned short* __restrict__ Bm,
    const float* __restrict__ bias,
    unsigned short* __restrict__ C,
    int M, int N, int K) {
  __shared__ unsigned short As[BM * BK];  // 16 KB
  __shared__ unsigned short Bs[BN * BK];  // 16 KB

  const int tid  = threadIdx.x;
  const int lane = tid & 63;
  const int wid  = tid >> 6;
  const int wm   = wid >> 1;     // wave row 0..1
  const int wn   = wid & 1;      // wave col 0..1
  const int l16  = lane & 15;
  const int quad = lane >> 4;

  const int rowBase = blockIdx.y * BM;
  const int colBase = blockIdx.x * BN;

  f32x4 acc[4][4] = {};

  for (int k0 = 0; k0 < K; k0 += BK) {
#pragma unroll
    for (int it = 0; it < 4; ++it) {
      // chunk index space [0,1024): row = c>>3, k-offset = (c&7)*8
      int cb = it * 256 + wid * 64;      // wave-uniform chunk base
      int c  = cb + lane;
      int row = c >> 3;
      int kk  = (c & 7) << 3;
      const unsigned short* ga = A + (size_t)(rowBase + row) * K + (k0 + kk);
      __builtin_amdgcn_global_load_lds(
          (const __attribute__((address_space(1))) void*)ga,
          (__attribute__((address_space(3))) void*)(As + (size_t)cb * 8), 16, 0, 0);
      const unsigned short* gb = Bm + (size_t)(colBase + row) * K + (k0 + kk);
      __builtin_amdgcn_global_load_lds(
          (const __attribute__((address_space(1))) void*)gb,
          (__attribute__((address_space(3))) void*)(Bs + (size_t)cb * 8), 16, 0, 0);
    }
    __syncthreads();  // drains vmcnt -> LDS tiles valid

#pragma unroll
    for (int kk = 0; kk < BK; kk += 32) {
      bf16x8 af[4], bfr[4];
#pragma unroll
      for (int mt = 0; mt < 4; ++mt)
        af[mt] = *(const bf16x8*)(As + (wm * 64 + mt * 16 + l16) * BK + kk + quad * 8);
#pragma unroll
      for (int nt = 0; nt < 4; ++nt)
        bfr[nt] = *(const bf16x8*)(Bs + (wn * 64 + nt * 16 + l16) * BK + kk + quad * 8);
#pragma unroll
      for (int mt = 0; mt < 4; ++mt)
#pragma unroll
        for (int nt = 0; nt < 4; ++nt)
          acc[mt][nt] = __builtin_amdgcn_mfma_f32_16x16x32_bf16(af[mt], bfr[nt], acc[mt][nt], 0, 0, 0);
    }
    __syncthreads();  // before restaging LDS
  }

  // epilogue: + bias, ReLU, bf16 store
  float bvals[4];
#pragma unroll
  for (int nt = 0; nt < 4; ++nt) bvals[nt] = bias[colBase + wn * 64 + nt * 16 + l16];

#pragma unroll
  for (int mt = 0; mt < 4; ++mt) {
#pragma unroll
    for (int r = 0; r < 4; ++r) {
      int row = rowBase + wm * 64 + mt * 16 + quad * 4 + r;
      unsigned short* cp = C + (size_t)row * N + colBase + wn * 64 + l16;
#pragma unroll
      for (int nt = 0; nt < 4; ++nt) {
        float v = acc[mt][nt][r] + bvals[nt];
        v = fmaxf(v, 0.0f);
        cp[nt * 16] = f2b(v);
      }
    }
  }
}

// ---------------- K3: GEMM3 (512->4) + per-scene routed 2x2 affines ----------------
// one wave per batch row: lane holds 8 of 512 h2 elements.
__global__ __launch_bounds__(256) void head_kernel(
    const unsigned short* __restrict__ h2,  // [B,512] bf16
    const float* __restrict__ W3,           // [4,512]
    const float* __restrict__ b3,           // [4]
    const int* __restrict__ sidx,           // [B] int32
    const float* __restrict__ xyW,          // [72,2,2]
    const float* __restrict__ xyb,          // [72,2]
    const float* __restrict__ tW,           // [72,2,2]
    float* __restrict__ out) {              // [B,4]
  int wave = (blockIdx.x * blockDim.x + threadIdx.x) >> 6;
  int lane = threadIdx.x & 63;
  if (wave >= BROWS) return;

  bf16x8 hv = *(const bf16x8*)(h2 + (size_t)wave * 512 + lane * 8);
  float hf[8];
#pragma unroll
  for (int j = 0; j < 8; ++j) hf[j] = (float)hv[j];

  float s[4];
#pragma unroll
  for (int o = 0; o < 4; ++o) {
    const float* wrow = W3 + o * 512 + lane * 8;
    float4 w0 = ((const float4*)wrow)[0];
    float4 w1 = ((const float4*)wrow)[1];
    float a = hf[0] * w0.x + hf[1] * w0.y + hf[2] * w0.z + hf[3] * w0.w +
              hf[4] * w1.x + hf[5] * w1.y + hf[6] * w1.z + hf[7] * w1.w;
#pragma unroll
    for (int off = 32; off > 0; off >>= 1) a += __shfl_down(a, off, 64);
    s[o] = a;
  }

  if (lane == 0) {
#pragma unroll
    for (int o = 0; o < 4; ++o) s[o] += b3[o];
    int sc = sidx[wave];
    const float* wx = xyW + sc * 4;
    const float* bx = xyb + sc * 2;
    const float* wt = tW + sc * 4;
    float o0 = wx[0] * s[0] + wx[1] * s[1] + bx[0];
    float o1 = wx[2] * s[0] + wx[3] * s[1] + bx[1];
    float o2 = wt[0] * s[2] + wt[1] * s[3];
    float o3 = wt[2] * s[2] + wt[3] * s[3];
    ((float4*)out)[wave] = make_float4(o0, o1, o2, o3);
  }
}

// ---------------- workspace layout (bytes) ----------------
#define WS_FEATB 0
#define WS_W1B   125829120UL              // 8192*7680*2
#define WS_W2B   133693440UL              // + 512*7680*2
#define WS_H1    134217728UL              // + 512*512*2
#define WS_H2    142606336UL              // + 8192*512*2
#define WS_NEED  150994944UL              // + 8192*512*2

extern "C" void kernel_launch(void* const* d_in, const int* in_sizes, int n_in,
                              void* d_out, int out_size, void* d_ws, size_t ws_size,
                              hipStream_t stream) {
  const float* feat = (const float*)d_in[0];
  const int*   sidx = (const int*)d_in[1];
  const float* W1   = (const float*)d_in[2];
  const float* b1   = (const float*)d_in[3];
  const float* W2   = (const float*)d_in[4];
  const float* b2   = (const float*)d_in[5];
  const float* W3   = (const float*)d_in[6];
  const float* b3   = (const float*)d_in[7];
  const float* xyW  = (const float*)d_in[8];
  const float* xyb  = (const float*)d_in[9];
  const float* tW   = (const float*)d_in[10];
  float* out = (float*)d_out;

  if (ws_size < WS_NEED) return;  // constant per-session; avoids heap corruption

  char* ws = (char*)d_ws;
  unsigned short* featB = (unsigned short*)(ws + WS_FEATB);
  unsigned short* W1B   = (unsigned short*)(ws + WS_W1B);
  unsigned short* W2B   = (unsigned short*)(ws + WS_W2B);
  unsigned short* h1    = (unsigned short*)(ws + WS_H1);
  unsigned short* h2    = (unsigned short*)(ws + WS_H2);

  // K0: convert fp32 -> bf16 (feat, W1, W2)
  cvt_kernel<<<4096, 256, 0, stream>>>(feat, featB, (BROWS * FEATK) / 4);
  cvt_kernel<<<512, 256, 0, stream>>>(W1, W1B, (HIDN * FEATK) / 4);
  cvt_kernel<<<64, 256, 0, stream>>>(W2, W2B, (HIDN * HIDN) / 4);

  // K1: h1 = relu(feat @ W1^T + b1)   [8192,512]
  gemm_bt_bias_relu<<<dim3(HIDN / BN, BROWS / BM), 256, 0, stream>>>(
      featB, W1B, b1, h1, BROWS, HIDN, FEATK);

  // K2: h2 = relu(h1 @ W2^T + b2)     [8192,512]
  gemm_bt_bias_relu<<<dim3(HIDN / BN, BROWS / BM), 256, 0, stream>>>(
      h1, W2B, b2, h2, BROWS, HIDN, HIDN);

  // K3: shared = h2 @ W3^T + b3 ; routed 2x2 affines -> out [8192,4]
  head_kernel<<<(BROWS * 64) / 256, 256, 0, stream>>>(
      h2, W3, b3, sidx, xyW, xyb, tW, out);
}

// Round 2
// 532.881 us; speedup vs baseline: 1.1034x; 1.1034x over previous
//
#include <hip/hip_runtime.h>
#include <stdint.h>
#include <stddef.h>

// Problem constants
#define BROWS 8192
#define FEATK 7680
#define HIDN  512

typedef __attribute__((ext_vector_type(8))) __bf16 bf16x8;
typedef __attribute__((ext_vector_type(4))) float f32x4;

// fp32 -> bf16 round-to-nearest-even (bit manip; inputs finite)
__device__ __forceinline__ unsigned short f2b(float f) {
  unsigned int u = __float_as_uint(f);
  unsigned int r = (u + 0x7FFFu + ((u >> 16) & 1u)) >> 16;
  return (unsigned short)r;
}

// ---------------- K0: fp32 -> bf16 conversion (vectorized, grid-stride) ----------------
__global__ void cvt_kernel(const float* __restrict__ src, unsigned short* __restrict__ dst, int n4) {
  int i = blockIdx.x * blockDim.x + threadIdx.x;
  int stride = gridDim.x * blockDim.x;
  for (; i < n4; i += stride) {
    float4 v = ((const float4*)src)[i];
    ushort4 o;
    o.x = f2b(v.x); o.y = f2b(v.y); o.z = f2b(v.z); o.w = f2b(v.w);
    ((ushort4*)dst)[i] = o;
  }
}

// ---------------- bf16 GEMM tile machinery (m97 structure) ----------------
// A: [M,K] bf16 row-major; Bm: [N,K] bf16 row-major; 128x128 block tile, BK=64,
// 256 threads (2x2 waves of 64x64), 16x16x32 bf16 MFMA, global_load_lds w=16.
#define BM 128
#define BN 128
#define BK 64

// Shared tile-compute body: accumulates over [k_begin, k_begin+klen) into acc.
#define GEMM_BODY(As, Bs, A, Bm, K, rowBase, colBase, k_begin, klen, acc)        \
  for (int k0 = (k_begin); k0 < (k_begin) + (klen); k0 += BK) {                  \
    _Pragma("unroll")                                                            \
    for (int it = 0; it < 4; ++it) {                                             \
      int cb = it * 256 + wid * 64;                                              \
      int c  = cb + lane;                                                        \
      int row = c >> 3;                                                          \
      int kk  = (c & 7) << 3;                                                    \
      const unsigned short* ga = A + (size_t)(rowBase + row) * K + (k0 + kk);    \
      __builtin_amdgcn_global_load_lds(                                          \
          (const __attribute__((address_space(1))) void*)ga,                     \
          (__attribute__((address_space(3))) void*)(As + (size_t)cb * 8), 16, 0, 0); \
      const unsigned short* gb = Bm + (size_t)(colBase + row) * K + (k0 + kk);   \
      __builtin_amdgcn_global_load_lds(                                          \
          (const __attribute__((address_space(1))) void*)gb,                     \
          (__attribute__((address_space(3))) void*)(Bs + (size_t)cb * 8), 16, 0, 0); \
    }                                                                            \
    __syncthreads();                                                             \
    _Pragma("unroll")                                                            \
    for (int kk = 0; kk < BK; kk += 32) {                                        \
      bf16x8 af[4], bfr[4];                                                      \
      _Pragma("unroll")                                                          \
      for (int mt = 0; mt < 4; ++mt)                                             \
        af[mt] = *(const bf16x8*)(As + (wm * 64 + mt * 16 + l16) * BK + kk + quad * 8); \
      _Pragma("unroll")                                                          \
      for (int nt = 0; nt < 4; ++nt)                                             \
        bfr[nt] = *(const bf16x8*)(Bs + (wn * 64 + nt * 16 + l16) * BK + kk + quad * 8); \
      _Pragma("unroll")                                                          \
      for (int mt = 0; mt < 4; ++mt)                                             \
        _Pragma("unroll")                                                        \
        for (int nt = 0; nt < 4; ++nt)                                           \
          acc[mt][nt] = __builtin_amdgcn_mfma_f32_16x16x32_bf16(af[mt], bfr[nt], acc[mt][nt], 0, 0, 0); \
    }                                                                            \
    __syncthreads();                                                             \
  }

// Fused single-pass GEMM: C = relu(A @ B^T + bias), bf16 out. (used for K2 / fallback)
__global__ __launch_bounds__(256, 2) void gemm_bt_bias_relu(
    const unsigned short* __restrict__ A,
    const unsigned short* __restrict__ Bm,
    const float* __restrict__ bias,
    unsigned short* __restrict__ C,
    int M, int N, int K) {
  __shared__ unsigned short As[BM * BK];
  __shared__ unsigned short Bs[BN * BK];
  const int tid  = threadIdx.x;
  const int lane = tid & 63;
  const int wid  = tid >> 6;
  const int wm   = wid >> 1;
  const int wn   = wid & 1;
  const int l16  = lane & 15;
  const int quad = lane >> 4;
  const int rowBase = blockIdx.y * BM;
  const int colBase = blockIdx.x * BN;

  f32x4 acc[4][4] = {};
  GEMM_BODY(As, Bs, A, Bm, K, rowBase, colBase, 0, K, acc)

  float bvals[4];
#pragma unroll
  for (int nt = 0; nt < 4; ++nt) bvals[nt] = bias[colBase + wn * 64 + nt * 16 + l16];
#pragma unroll
  for (int mt = 0; mt < 4; ++mt) {
#pragma unroll
    for (int r = 0; r < 4; ++r) {
      int row = rowBase + wm * 64 + mt * 16 + quad * 4 + r;
      unsigned short* cp = C + (size_t)row * N + colBase + wn * 64 + l16;
#pragma unroll
      for (int nt = 0; nt < 4; ++nt) {
        float v = fmaxf(acc[mt][nt][r] + bvals[nt], 0.0f);
        cp[nt * 16] = f2b(v);
      }
    }
  }
}

// Split-K GEMM: P[s] = A @ B^T over k-chunk s. fp32 partials, no epilogue.
__global__ __launch_bounds__(256, 2) void gemm_bt_splitk(
    const unsigned short* __restrict__ A,
    const unsigned short* __restrict__ Bm,
    float* __restrict__ P,
    int M, int N, int K, int klen) {
  __shared__ unsigned short As[BM * BK];
  __shared__ unsigned short Bs[BN * BK];
  const int tid  = threadIdx.x;
  const int lane = tid & 63;
  const int wid  = tid >> 6;
  const int wm   = wid >> 1;
  const int wn   = wid & 1;
  const int l16  = lane & 15;
  const int quad = lane >> 4;
  const int rowBase = blockIdx.y * BM;
  const int colBase = blockIdx.x * BN;
  const int k_begin = blockIdx.z * klen;

  f32x4 acc[4][4] = {};
  GEMM_BODY(As, Bs, A, Bm, K, rowBase, colBase, k_begin, klen, acc)

  float* outp = P + (size_t)blockIdx.z * M * N;
#pragma unroll
  for (int mt = 0; mt < 4; ++mt) {
#pragma unroll
    for (int r = 0; r < 4; ++r) {
      int row = rowBase + wm * 64 + mt * 16 + quad * 4 + r;
      float* cp = outp + (size_t)row * N + colBase + wn * 64 + l16;
#pragma unroll
      for (int nt = 0; nt < 4; ++nt) cp[nt * 16] = acc[mt][nt][r];
    }
  }
}

// Reduce S=4 partials + bias + ReLU -> bf16
__global__ __launch_bounds__(256) void reduce4_bias_relu(
    const float* __restrict__ P, const float* __restrict__ bias,
    unsigned short* __restrict__ H, int MN4, int N4) {
  int i = blockIdx.x * blockDim.x + threadIdx.x;
  if (i >= MN4) return;
  const float4* p = (const float4*)P;
  float4 a = p[i];
  float4 b = p[i + MN4];
  float4 c = p[i + 2 * MN4];
  float4 d = p[i + 3 * MN4];
  float4 bs = ((const float4*)bias)[i % N4];
  ushort4 o;
  o.x = f2b(fmaxf(a.x + b.x + c.x + d.x + bs.x, 0.0f));
  o.y = f2b(fmaxf(a.y + b.y + c.y + d.y + bs.y, 0.0f));
  o.z = f2b(fmaxf(a.z + b.z + c.z + d.z + bs.z, 0.0f));
  o.w = f2b(fmaxf(a.w + b.w + c.w + d.w + bs.w, 0.0f));
  ((ushort4*)H)[i] = o;
}

// ---------------- K3: GEMM3 (512->4) + per-scene routed 2x2 affines ----------------
__global__ __launch_bounds__(256) void head_kernel(
    const unsigned short* __restrict__ h2,  // [B,512] bf16
    const float* __restrict__ W3,           // [4,512]
    const float* __restrict__ b3,           // [4]
    const int* __restrict__ sidx,           // [B] int32
    const float* __restrict__ xyW,          // [72,2,2]
    const float* __restrict__ xyb,          // [72,2]
    const float* __restrict__ tW,           // [72,2,2]
    float* __restrict__ out) {              // [B,4]
  int wave = (blockIdx.x * blockDim.x + threadIdx.x) >> 6;
  int lane = threadIdx.x & 63;
  if (wave >= BROWS) return;

  bf16x8 hv = *(const bf16x8*)(h2 + (size_t)wave * 512 + lane * 8);
  float hf[8];
#pragma unroll
  for (int j = 0; j < 8; ++j) hf[j] = (float)hv[j];

  float s[4];
#pragma unroll
  for (int o = 0; o < 4; ++o) {
    const float* wrow = W3 + o * 512 + lane * 8;
    float4 w0 = ((const float4*)wrow)[0];
    float4 w1 = ((const float4*)wrow)[1];
    float a = hf[0] * w0.x + hf[1] * w0.y + hf[2] * w0.z + hf[3] * w0.w +
              hf[4] * w1.x + hf[5] * w1.y + hf[6] * w1.z + hf[7] * w1.w;
#pragma unroll
    for (int off = 32; off > 0; off >>= 1) a += __shfl_down(a, off, 64);
    s[o] = a;
  }

  if (lane == 0) {
#pragma unroll
    for (int o = 0; o < 4; ++o) s[o] += b3[o];
    int sc = sidx[wave];
    const float* wx = xyW + sc * 4;
    const float* bx = xyb + sc * 2;
    const float* wt = tW + sc * 4;
    float o0 = wx[0] * s[0] + wx[1] * s[1] + bx[0];
    float o1 = wx[2] * s[0] + wx[3] * s[1] + bx[1];
    float o2 = wt[0] * s[2] + wt[1] * s[3];
    float o3 = wt[2] * s[2] + wt[3] * s[3];
    ((float4*)out)[wave] = make_float4(o0, o1, o2, o3);
  }
}

// ---------------- workspace layout (bytes) ----------------
#define WS_FEATB 0
#define WS_W1B   125829120UL              // 8192*7680*2
#define WS_W2B   133693440UL              // + 512*7680*2
#define WS_H1    134217728UL              // + 512*512*2
#define WS_H2    142606336UL              // + 8192*512*2
#define WS_PART  150994944UL              // + 8192*512*2
#define WS_BASE  150994944UL
#define WS_SPLITK (150994944UL + 4UL * 8192UL * 512UL * 4UL)  // + 67 MB partials

extern "C" void kernel_launch(void* const* d_in, const int* in_sizes, int n_in,
                              void* d_out, int out_size, void* d_ws, size_t ws_size,
                              hipStream_t stream) {
  const float* feat = (const float*)d_in[0];
  const int*   sidx = (const int*)d_in[1];
  const float* W1   = (const float*)d_in[2];
  const float* b1   = (const float*)d_in[3];
  const float* W2   = (const float*)d_in[4];
  const float* b2   = (const float*)d_in[5];
  const float* W3   = (const float*)d_in[6];
  const float* b3   = (const float*)d_in[7];
  const float* xyW  = (const float*)d_in[8];
  const float* xyb  = (const float*)d_in[9];
  const float* tW   = (const float*)d_in[10];
  float* out = (float*)d_out;

  if (ws_size < WS_BASE) return;

  char* ws = (char*)d_ws;
  unsigned short* featB = (unsigned short*)(ws + WS_FEATB);
  unsigned short* W1B   = (unsigned short*)(ws + WS_W1B);
  unsigned short* W2B   = (unsigned short*)(ws + WS_W2B);
  unsigned short* h1    = (unsigned short*)(ws + WS_H1);
  unsigned short* h2    = (unsigned short*)(ws + WS_H2);
  float*          part  = (float*)(ws + WS_PART);

  // K0: convert fp32 -> bf16 (feat, W1, W2)
  cvt_kernel<<<4096, 256, 0, stream>>>(feat, featB, (BROWS * FEATK) / 4);
  cvt_kernel<<<512, 256, 0, stream>>>(W1, W1B, (HIDN * FEATK) / 4);
  cvt_kernel<<<64, 256, 0, stream>>>(W2, W2B, (HIDN * HIDN) / 4);

  // K1: h1 = relu(feat @ W1^T + b1)   [8192,512]
  if (ws_size >= WS_SPLITK) {
    // split-K S=4: grid 1024 blocks -> ~4 blocks/CU (vs 256 -> 1/CU)
    gemm_bt_splitk<<<dim3(HIDN / BN, BROWS / BM, 4), 256, 0, stream>>>(
        featB, W1B, part, BROWS, HIDN, FEATK, FEATK / 4);
    reduce4_bias_relu<<<(BROWS * HIDN / 4 + 255) / 256, 256, 0, stream>>>(
        part, b1, h1, BROWS * HIDN / 4, HIDN / 4);
  } else {
    gemm_bt_bias_relu<<<dim3(HIDN / BN, BROWS / BM), 256, 0, stream>>>(
        featB, W1B, b1, h1, BROWS, HIDN, FEATK);
  }

  // K2: h2 = relu(h1 @ W2^T + b2)     [8192,512]
  gemm_bt_bias_relu<<<dim3(HIDN / BN, BROWS / BM), 256, 0, stream>>>(
      h1, W2B, b2, h2, BROWS, HIDN, HIDN);

  // K3: shared = h2 @ W3^T + b3 ; routed 2x2 affines -> out [8192,4]
  head_kernel<<<(BROWS * 64) / 256, 256, 0, stream>>>(
      h2, W3, b3, sidx, xyW, xyb, tW, out);
}

// Round 3
// 480.365 us; speedup vs baseline: 1.2240x; 1.1093x over previous
//
#include <hip/hip_runtime.h>
#include <stdint.h>
#include <stddef.h>

// Problem constants
#define BROWS 8192
#define FEATK 7680
#define HIDN  512

typedef __attribute__((ext_vector_type(8))) __bf16 bf16x8;
typedef __attribute__((ext_vector_type(4))) float f32x4;

// fp32 -> bf16 round-to-nearest-even (bit manip; inputs finite)
__device__ __forceinline__ unsigned short f2b(float f) {
  unsigned int u = __float_as_uint(f);
  unsigned int r = (u + 0x7FFFu + ((u >> 16) & 1u)) >> 16;
  return (unsigned short)r;
}

// ---------------- K0: fp32 -> bf16 conversion (weights only now) ----------------
__global__ void cvt_kernel(const float* __restrict__ src, unsigned short* __restrict__ dst, int n4) {
  int i = blockIdx.x * blockDim.x + threadIdx.x;
  int stride = gridDim.x * blockDim.x;
  for (; i < n4; i += stride) {
    float4 v = ((const float4*)src)[i];
    ushort4 o;
    o.x = f2b(v.x); o.y = f2b(v.y); o.z = f2b(v.z); o.w = f2b(v.w);
    ((ushort4*)dst)[i] = o;
  }
}

// ---------------- K1: fused fp32-A GEMM, split-K ----------------
// P[s] += A(fp32)[64-row stripe] @ W1B(bf16)^T over k-chunk s. Full N=512 per block.
// BM=64, BN=512, BK=32. 256 threads = 4 waves; wave w computes 64 rows x cols [w*128,+128)
// as 4x8 grid of 16x16 tiles. A converted fp32->bf16 in-register during LDS staging;
// B staged with global_load_lds width=16.
#define K1_BM 64
#define K1_BK 32

__global__ __launch_bounds__(256, 2) void gemm1_fused_splitk(
    const float* __restrict__ A,            // [8192, 7680] fp32
    const unsigned short* __restrict__ Bm,  // [512, 7680] bf16
    float* __restrict__ P,                  // [S, 8192, 512] fp32 partials
    int M, int N, int K, int klen) {
  __shared__ unsigned short As[K1_BM * K1_BK];   // 4 KB
  __shared__ unsigned short Bs[HIDN * K1_BK];    // 32 KB

  const int tid  = threadIdx.x;
  const int lane = tid & 63;
  const int wid  = tid >> 6;
  const int l16  = lane & 15;
  const int quad = lane >> 4;

  const int rowBase = blockIdx.y * K1_BM;
  const int k_begin = blockIdx.x * klen;

  f32x4 acc[4][8] = {};

  for (int k0 = k_begin; k0 < k_begin + klen; k0 += K1_BK) {
    // ---- stage A: 64x32 fp32 -> bf16 -> LDS (row-major, stride 32) ----
#pragma unroll
    for (int it = 0; it < 2; ++it) {
      int c   = it * 256 + tid;        // float4 index in [0, 512)
      int row = c >> 3;                // 8 float4 per row (32 fp32)
      int kq  = c & 7;
      const float4* ga = (const float4*)(A + (size_t)(rowBase + row) * K + k0 + kq * 4);
      float4 v = *ga;
      ushort4 o;
      o.x = f2b(v.x); o.y = f2b(v.y); o.z = f2b(v.z); o.w = f2b(v.w);
      *(ushort4*)(As + row * K1_BK + kq * 4) = o;
    }
    // ---- stage B: 512x32 bf16 via global_load_lds (16B chunks) ----
#pragma unroll
    for (int it = 0; it < 8; ++it) {
      int cb  = it * 256 + wid * 64;   // wave-uniform chunk base
      int c   = cb + lane;             // 16B-chunk index in [0, 2048)
      int row = c >> 2;                // 4 chunks per row (32 bf16 = 64B)
      int kk  = (c & 3) << 3;          // short offset within row
      const unsigned short* gb = Bm + (size_t)row * K + (k0 + kk);
      __builtin_amdgcn_global_load_lds(
          (const __attribute__((address_space(1))) void*)gb,
          (__attribute__((address_space(3))) void*)(Bs + (size_t)cb * 8), 16, 0, 0);
    }
    __syncthreads();

    // ---- compute: one 16x16x32 MFMA per tile ----
    bf16x8 af[4], bfr[8];
#pragma unroll
    for (int mt = 0; mt < 4; ++mt)
      af[mt] = *(const bf16x8*)(As + (mt * 16 + l16) * K1_BK + quad * 8);
#pragma unroll
    for (int nt = 0; nt < 8; ++nt)
      bfr[nt] = *(const bf16x8*)(Bs + (wid * 128 + nt * 16 + l16) * K1_BK + quad * 8);
#pragma unroll
    for (int mt = 0; mt < 4; ++mt)
#pragma unroll
      for (int nt = 0; nt < 8; ++nt)
        acc[mt][nt] = __builtin_amdgcn_mfma_f32_16x16x32_bf16(af[mt], bfr[nt], acc[mt][nt], 0, 0, 0);
    __syncthreads();
  }

  // ---- epilogue: fp32 partials ----
  float* outp = P + (size_t)blockIdx.x * M * N;
#pragma unroll
  for (int mt = 0; mt < 4; ++mt) {
#pragma unroll
    for (int r = 0; r < 4; ++r) {
      int row = rowBase + mt * 16 + quad * 4 + r;
      float* cp = outp + (size_t)row * N + wid * 128 + l16;
#pragma unroll
      for (int nt = 0; nt < 8; ++nt) cp[nt * 16] = acc[mt][nt][r];
    }
  }
}

// Reduce S=4 partials + bias + ReLU -> bf16
__global__ __launch_bounds__(256) void reduce4_bias_relu(
    const float* __restrict__ P, const float* __restrict__ bias,
    unsigned short* __restrict__ H, int MN4, int N4) {
  int i = blockIdx.x * blockDim.x + threadIdx.x;
  if (i >= MN4) return;
  const float4* p = (const float4*)P;
  float4 a = p[i];
  float4 b = p[i + MN4];
  float4 c = p[i + 2 * MN4];
  float4 d = p[i + 3 * MN4];
  float4 bs = ((const float4*)bias)[i % N4];
  ushort4 o;
  o.x = f2b(fmaxf(a.x + b.x + c.x + d.x + bs.x, 0.0f));
  o.y = f2b(fmaxf(a.y + b.y + c.y + d.y + bs.y, 0.0f));
  o.z = f2b(fmaxf(a.z + b.z + c.z + d.z + bs.z, 0.0f));
  o.w = f2b(fmaxf(a.w + b.w + c.w + d.w + bs.w, 0.0f));
  ((ushort4*)H)[i] = o;
}

// ---------------- K2: bf16 GEMM  C = relu(A @ B^T + bias) (m97 structure) ----------------
#define BM 128
#define BN 128
#define BK 64

__global__ __launch_bounds__(256, 2) void gemm_bt_bias_relu(
    const unsigned short* __restrict__ A,
    const unsigned short* __restrict__ Bm,
    const float* __restrict__ bias,
    unsigned short* __restrict__ C,
    int M, int N, int K) {
  __shared__ unsigned short As[BM * BK];
  __shared__ unsigned short Bs[BN * BK];
  const int tid  = threadIdx.x;
  const int lane = tid & 63;
  const int wid  = tid >> 6;
  const int wm   = wid >> 1;
  const int wn   = wid & 1;
  const int l16  = lane & 15;
  const int quad = lane >> 4;
  const int rowBase = blockIdx.y * BM;
  const int colBase = blockIdx.x * BN;

  f32x4 acc[4][4] = {};

  for (int k0 = 0; k0 < K; k0 += BK) {
#pragma unroll
    for (int it = 0; it < 4; ++it) {
      int cb = it * 256 + wid * 64;
      int c  = cb + lane;
      int row = c >> 3;
      int kk  = (c & 7) << 3;
      const unsigned short* ga = A + (size_t)(rowBase + row) * K + (k0 + kk);
      __builtin_amdgcn_global_load_lds(
          (const __attribute__((address_space(1))) void*)ga,
          (__attribute__((address_space(3))) void*)(As + (size_t)cb * 8), 16, 0, 0);
      const unsigned short* gb = Bm + (size_t)(colBase + row) * K + (k0 + kk);
      __builtin_amdgcn_global_load_lds(
          (const __attribute__((address_space(1))) void*)gb,
          (__attribute__((address_space(3))) void*)(Bs + (size_t)cb * 8), 16, 0, 0);
    }
    __syncthreads();
#pragma unroll
    for (int kk = 0; kk < BK; kk += 32) {
      bf16x8 af[4], bfr[4];
#pragma unroll
      for (int mt = 0; mt < 4; ++mt)
        af[mt] = *(const bf16x8*)(As + (wm * 64 + mt * 16 + l16) * BK + kk + quad * 8);
#pragma unroll
      for (int nt = 0; nt < 4; ++nt)
        bfr[nt] = *(const bf16x8*)(Bs + (wn * 64 + nt * 16 + l16) * BK + kk + quad * 8);
#pragma unroll
      for (int mt = 0; mt < 4; ++mt)
#pragma unroll
        for (int nt = 0; nt < 4; ++nt)
          acc[mt][nt] = __builtin_amdgcn_mfma_f32_16x16x32_bf16(af[mt], bfr[nt], acc[mt][nt], 0, 0, 0);
    }
    __syncthreads();
  }

  float bvals[4];
#pragma unroll
  for (int nt = 0; nt < 4; ++nt) bvals[nt] = bias[colBase + wn * 64 + nt * 16 + l16];
#pragma unroll
  for (int mt = 0; mt < 4; ++mt) {
#pragma unroll
    for (int r = 0; r < 4; ++r) {
      int row = rowBase + wm * 64 + mt * 16 + quad * 4 + r;
      unsigned short* cp = C + (size_t)row * N + colBase + wn * 64 + l16;
#pragma unroll
      for (int nt = 0; nt < 4; ++nt) {
        float v = fmaxf(acc[mt][nt][r] + bvals[nt], 0.0f);
        cp[nt * 16] = f2b(v);
      }
    }
  }
}

// ---------------- K3: GEMM3 (512->4) + per-scene routed 2x2 affines ----------------
__global__ __launch_bounds__(256) void head_kernel(
    const unsigned short* __restrict__ h2,  // [B,512] bf16
    const float* __restrict__ W3,           // [4,512]
    const float* __restrict__ b3,           // [4]
    const int* __restrict__ sidx,           // [B] int32
    const float* __restrict__ xyW,          // [72,2,2]
    const float* __restrict__ xyb,          // [72,2]
    const float* __restrict__ tW,           // [72,2,2]
    float* __restrict__ out) {              // [B,4]
  int wave = (blockIdx.x * blockDim.x + threadIdx.x) >> 6;
  int lane = threadIdx.x & 63;
  if (wave >= BROWS) return;

  bf16x8 hv = *(const bf16x8*)(h2 + (size_t)wave * 512 + lane * 8);
  float hf[8];
#pragma unroll
  for (int j = 0; j < 8; ++j) hf[j] = (float)hv[j];

  float s[4];
#pragma unroll
  for (int o = 0; o < 4; ++o) {
    const float* wrow = W3 + o * 512 + lane * 8;
    float4 w0 = ((const float4*)wrow)[0];
    float4 w1 = ((const float4*)wrow)[1];
    float a = hf[0] * w0.x + hf[1] * w0.y + hf[2] * w0.z + hf[3] * w0.w +
              hf[4] * w1.x + hf[5] * w1.y + hf[6] * w1.z + hf[7] * w1.w;
#pragma unroll
    for (int off = 32; off > 0; off >>= 1) a += __shfl_down(a, off, 64);
    s[o] = a;
  }

  if (lane == 0) {
#pragma unroll
    for (int o = 0; o < 4; ++o) s[o] += b3[o];
    int sc = sidx[wave];
    const float* wx = xyW + sc * 4;
    const float* bx = xyb + sc * 2;
    const float* wt = tW + sc * 4;
    float o0 = wx[0] * s[0] + wx[1] * s[1] + bx[0];
    float o1 = wx[2] * s[0] + wx[3] * s[1] + bx[1];
    float o2 = wt[0] * s[2] + wt[1] * s[3];
    float o3 = wt[2] * s[2] + wt[3] * s[3];
    ((float4*)out)[wave] = make_float4(o0, o1, o2, o3);
  }
}

// ---------------- workspace layout (bytes) ----------------
#define WS_W1B   0UL                      // 512*7680*2  = 7864320
#define WS_W2B   7864320UL                // + 512*512*2 = 524288
#define WS_H1    8388608UL                // + 8192*512*2
#define WS_H2    16777216UL               // + 8192*512*2
#define WS_PART  25165824UL               // + 4*8192*512*4 = 67108864
#define WS_NEED  92274688UL

extern "C" void kernel_launch(void* const* d_in, const int* in_sizes, int n_in,
                              void* d_out, int out_size, void* d_ws, size_t ws_size,
                              hipStream_t stream) {
  const float* feat = (const float*)d_in[0];
  const int*   sidx = (const int*)d_in[1];
  const float* W1   = (const float*)d_in[2];
  const float* b1   = (const float*)d_in[3];
  const float* W2   = (const float*)d_in[4];
  const float* b2   = (const float*)d_in[5];
  const float* W3   = (const float*)d_in[6];
  const float* b3   = (const float*)d_in[7];
  const float* xyW  = (const float*)d_in[8];
  const float* xyb  = (const float*)d_in[9];
  const float* tW   = (const float*)d_in[10];
  float* out = (float*)d_out;

  if (ws_size < WS_NEED) return;  // ws observed ~1 GB; guard only

  char* ws = (char*)d_ws;
  unsigned short* W1B  = (unsigned short*)(ws + WS_W1B);
  unsigned short* W2B  = (unsigned short*)(ws + WS_W2B);
  unsigned short* h1   = (unsigned short*)(ws + WS_H1);
  unsigned short* h2   = (unsigned short*)(ws + WS_H2);
  float*          part = (float*)(ws + WS_PART);

  // K0: convert weights fp32 -> bf16 (feat stays fp32, converted in-GEMM)
  cvt_kernel<<<512, 256, 0, stream>>>(W1, W1B, (HIDN * FEATK) / 4);
  cvt_kernel<<<64, 256, 0, stream>>>(W2, W2B, (HIDN * HIDN) / 4);

  // K1: partials = feat @ W1^T (split-K S=4, fused fp32->bf16 on A)
  gemm1_fused_splitk<<<dim3(4, BROWS / K1_BM), 256, 0, stream>>>(
      feat, W1B, part, BROWS, HIDN, FEATK, FEATK / 4);
  reduce4_bias_relu<<<(BROWS * HIDN / 4 + 255) / 256, 256, 0, stream>>>(
      part, b1, h1, BROWS * HIDN / 4, HIDN / 4);

  // K2: h2 = relu(h1 @ W2^T + b2)
  gemm_bt_bias_relu<<<dim3(HIDN / BN, BROWS / BM), 256, 0, stream>>>(
      h1, W2B, b2, h2, BROWS, HIDN, HIDN);

  // K3: shared = h2 @ W3^T + b3 ; routed 2x2 affines -> out
  head_kernel<<<(BROWS * 64) / 256, 256, 0, stream>>>(
      h2, W3, b3, sidx, xyW, xyb, tW, out);
}